// Round 18
// baseline (628.376 us; speedup 1.0000x reference)
//
#include <hip/hip_runtime.h>
#include <hip/hip_bf16.h>

#define BATCH  16384
#define SLOPE  0.2f
#define BM     32

typedef __attribute__((ext_vector_type(8))) short bf16x8;
typedef __attribute__((ext_vector_type(4))) float f32x4;
typedef __attribute__((ext_vector_type(4))) float fx4;
typedef __attribute__((ext_vector_type(2))) float fx2;

// ws layout (bf16 element offsets), weights TRANSPOSED as [N][K]; s/t contiguous.
// W0T and W2T rows are PRE-SWIZZLED in 16B units: unit u of row n at u ^ (n&7)
// (within each 128B chunk for W0T; within the 256B row for W2T).
#define OFF_SW0T 0         // [128][2048]
#define OFF_TW0T 262144
#define OFF_SW1T 524288    // [128][128] (unswizzled)
#define OFF_TW1T 540672
#define OFF_SW2T 557056    // [2048][128]
#define OFF_TW2T 819200

__device__ __forceinline__ unsigned short f2bf(float f) {
    unsigned int u = __float_as_uint(f);
    u += 0x7FFFu + ((u >> 16) & 1u);   // round-to-nearest-even
    return (unsigned short)(u >> 16);
}

__global__ void conv_w(const float* __restrict__ sW0, const float* __restrict__ sW1,
                       const float* __restrict__ sW2, const float* __restrict__ tW0,
                       const float* __restrict__ tW1, const float* __restrict__ tW2,
                       unsigned short* __restrict__ ws) {
    const int total = 262144 + 16384 + 262144;
    for (int i = blockIdx.x * blockDim.x + threadIdx.x; i < total;
         i += gridDim.x * blockDim.x) {
        if (i < 262144) {                    // W0 [2048][128] -> [128][2048], swz
            int k = i >> 7, n = i & 127;
            int ks = (k & ~63) | ((((k >> 3) & 7) ^ (n & 7)) << 3) | (k & 7);
            ws[OFF_SW0T + n * 2048 + ks] = f2bf(sW0[i]);
            ws[OFF_TW0T + n * 2048 + ks] = f2bf(tW0[i]);
        } else if (i < 262144 + 16384) {     // W1 [128][128] -> transpose (no swz)
            int j = i - 262144;
            int k = j >> 7, n = j & 127;
            ws[OFF_SW1T + n * 128 + k] = f2bf(sW1[j]);
            ws[OFF_TW1T + n * 128 + k] = f2bf(tW1[j]);
        } else {                             // W2 [128][2048] -> [2048][128], swz
            int j = i - (262144 + 16384);
            int k = j >> 11, n = j & 2047;
            int ks = ((((k >> 3) & 15) ^ (n & 7)) << 3) | (k & 7);
            ws[OFF_SW2T + n * 128 + ks] = f2bf(sW2[j]);
            ws[OFF_TW2T + n * 128 + ks] = f2bf(tW2[j]);
        }
    }
}

__global__ __launch_bounds__(256, 4) void coupling_main(
    const float* __restrict__ z,
    const float* __restrict__ s_b2,
    const float* __restrict__ t_b2,
    const unsigned short* __restrict__ ws,
    float* __restrict__ f_out,
    float* __restrict__ d_vec) {

    // LDS map (40960 B total -> 4 blocks/CU):
    //   L0: Az dbuf [0,8K) (2x4K) | W0 single [8K,40K) (32K, self-consumed rows)
    //   L1: HA [0,16K) | HB [16K,32K)        (L0 regions dead)
    //   L2: W2 single [0,32K) (self-consumed) | Dred [32K,32K+512)
    __shared__ __align__(16) unsigned char LDSbuf[40960];
    unsigned short* HA = (unsigned short*)(LDSbuf);
    unsigned short* HB = (unsigned short*)(LDSbuf + 16384);
    float* Dred = (float*)(LDSbuf + 32768);

    const int tid  = threadIdx.x;
    const int wave = tid >> 6;
    const int lane = tid & 63;
    const int l15  = lane & 15;
    const int l4   = lane >> 4;
    const int brow = blockIdx.x * BM;

    const char* wsb = (const char*)ws;
    const fx4* __restrict__ zf4 = (const fx4*)z;
    const fx2* __restrict__ zf2 = (const fx2*)z;
    fx2* __restrict__ ff2 = (fx2*)f_out;

    // ---- L0 staging helpers ----
    auto ldzTo = [&](fx4 (&zr)[4], int c) {
        #pragma unroll
        for (int q = 0; q < 4; ++q) {
            const int f = tid + 256 * q;
            const int row = f >> 5, col16 = f & 31;
            zr[q] = __builtin_nontemporal_load(
                zf4 + (size_t)(brow + row) * 1024 + c * 32 + col16);
        }
    };
    auto wrzFrom = [&](fx4 (&zr)[4], int b) {
        #pragma unroll
        for (int q = 0; q < 4; ++q) {
            const int f = tid + 256 * q;
            const int row = f >> 5, col16 = f & 31;
            const int par = (col16 >> 4) & 1;
            const float a0 = par ? zr[q].y : zr[q].x;
            const float a1 = par ? zr[q].w : zr[q].z;
            const unsigned int pk = (unsigned int)f2bf(a0) | ((unsigned int)f2bf(a1) << 16);
            *(unsigned int*)(LDSbuf + b * 4096 + row * 128 +
                             (((col16 >> 2) ^ (row & 7)) << 4) + (col16 & 3) * 4) = pk;
        }
    };
    // wave w stages exactly the 64 g-rows it reads -> self-consumed (no x-wave hazard)
    auto stageW0 = [&](int c) {
        #pragma unroll
        for (int jj = 0; jj < 8; ++jj) {
            const char* g = wsb + (size_t)(wave * 64 + jj * 8 + (lane >> 3)) * 4096
                            + c * 128 + (lane & 7) * 16;
            void* l = LDSbuf + 8192 + (wave * 64 + jj * 8) * 128;
            __builtin_amdgcn_global_load_lds(
                (const __attribute__((address_space(1))) unsigned int*)g,
                (__attribute__((address_space(3))) unsigned int*)l, 16, 0, 0);
        }
    };

    f32x4 acc0[2][4] = {};   // [m][n2]

    fx4 zA[4], zB[4];
    // Phase p (single-buffered W0, self-consumed):
    //   read Az(p)+W0(p) fragments -> regs; lgkm(0); overwrite own W0 rows with
    //   p+1's stage; issue z(p+2); MFMA from regs (covers stage); write Az(p+1);
    //   drain own stage (vmcnt leaves z loads) + Az ds_writes; barrier (Az only).
    auto phase = [&](int p, int cb, fx4 (&zLd)[4], fx4 (&zWr)[4]) {
        const char* Az = (const char*)(LDSbuf + cb * 4096);
        const char* Wt = (const char*)(LDSbuf + 8192);
        bf16x8 af[2][2], wf[4][2];
        #pragma unroll
        for (int m = 0; m < 2; ++m)
            #pragma unroll
            for (int k2 = 0; k2 < 2; ++k2) {
                const int row = m * 16 + l15;
                af[m][k2] = *(const bf16x8*)(Az + row * 128 +
                              ((k2 * 64 + l4 * 16) ^ ((row & 7) << 4)));
            }
        #pragma unroll
        for (int n2 = 0; n2 < 4; ++n2)
            #pragma unroll
            for (int k2 = 0; k2 < 2; ++k2) {
                const int g = wave * 64 + n2 * 16 + l15;
                wf[n2][k2] = *(const bf16x8*)(Wt + g * 128 +
                               ((k2 * 64 + l4 * 16) ^ ((g & 7) << 4)));
            }
        asm volatile("s_waitcnt lgkmcnt(0)" ::: "memory");   // own W0/Az reads done
        if (p + 1 < 32) stageW0(p + 1);                      // overwrite own rows
        if (p + 2 < 32) ldzTo(zLd, p + 2);
        #pragma unroll
        for (int n2 = 0; n2 < 4; ++n2)
            #pragma unroll
            for (int k2 = 0; k2 < 2; ++k2)
                #pragma unroll
                for (int m = 0; m < 2; ++m)
                    acc0[m][n2] = __builtin_amdgcn_mfma_f32_16x16x32_bf16(
                        af[m][k2], wf[n2][k2], acc0[m][n2], 0, 0, 0);
        if (p + 1 < 32) wrzFrom(zWr, cb ^ 1);
        if (p + 2 < 32)
            asm volatile("s_waitcnt lgkmcnt(0) vmcnt(4)" ::: "memory");
        else
            asm volatile("s_waitcnt lgkmcnt(0) vmcnt(0)" ::: "memory");
        __builtin_amdgcn_s_barrier();
        __builtin_amdgcn_sched_barrier(0);
    };

    // ---------------- layer 0: h0 = leaky(z_a @ W0), unified g in [0,256) ----------------
    ldzTo(zB, 0);
    stageW0(0);
    wrzFrom(zB, 0);          // Az0 <- tile 0 (compiler waits z(0))
    ldzTo(zB, 1);            // zB <- tile 1
    asm volatile("s_waitcnt lgkmcnt(0) vmcnt(4)" ::: "memory");   // drain W0(0), leave z(1)
    __builtin_amdgcn_s_barrier();
    __builtin_amdgcn_sched_barrier(0);

    #pragma unroll 1
    for (int gIt = 0; gIt < 16; ++gIt) {
        phase(2 * gIt,     0, zA, zB);
        phase(2 * gIt + 1, 1, zB, zA);
    }

    // leaky, h0 -> HA (swizzled [32][256])
    #pragma unroll
    for (int m = 0; m < 2; ++m)
        #pragma unroll
        for (int n2 = 0; n2 < 4; ++n2)
            #pragma unroll
            for (int r = 0; r < 4; ++r) {
                float v = acc0[m][n2][r];
                v = v > 0.0f ? v : SLOPE * v;
                const int row = m * 16 + l4 * 4 + r;
                const int col = wave * 64 + n2 * 16 + l15;
                HA[row * 256 + (col ^ ((row & 7) << 3))] = f2bf(v);
            }
    __syncthreads();

    // ---------------- layer 1: h1 = leaky(h0 @ W1) (direct global W1T) ----------------
    f32x4 acc1[2][4] = {};
    const int net1 = wave >> 1;
    #pragma unroll
    for (int k4 = 0; k4 < 4; ++k4) {
        bf16x8 ahv[2];
        #pragma unroll
        for (int m = 0; m < 2; ++m) {
            const int row = m * 16 + l15;
            ahv[m] = *(const bf16x8*)&HA[row * 256 +
                       ((net1 * 128 + k4 * 32 + l4 * 8) ^ ((row & 7) << 3))];
        }
        #pragma unroll
        for (int n2 = 0; n2 < 4; ++n2) {
            const bf16x8 w = *(const bf16x8*)&ws[OFF_SW1T +
                (size_t)(wave * 64 + n2 * 16 + l15) * 128 + k4 * 32 + l4 * 8];
            #pragma unroll
            for (int m = 0; m < 2; ++m)
                acc1[m][n2] = __builtin_amdgcn_mfma_f32_16x16x32_bf16(
                    ahv[m], w, acc1[m][n2], 0, 0, 0);
        }
    }
    __syncthreads();   // HA reads done
    #pragma unroll
    for (int m = 0; m < 2; ++m)
        #pragma unroll
        for (int n2 = 0; n2 < 4; ++n2)
            #pragma unroll
            for (int r = 0; r < 4; ++r) {
                float v = acc1[m][n2][r];
                v = v > 0.0f ? v : SLOPE * v;
                const int row = m * 16 + l4 * 4 + r;
                const int col = wave * 64 + n2 * 16 + l15;
                HB[row * 256 + (col ^ ((row & 7) << 3))] = f2bf(v);
            }
    __syncthreads();

    // ---------------- layer 2 + epilogue: single W2 tile, self-consumed, barrier-free ----------------
    const int par = wave >> 1;   // lattice-row parity of this wave's pairs

    // hoist A-fragments once (both nets)
    bf16x8 ahs[2][4], aht[2][4];   // [m][k4]
    #pragma unroll
    for (int m = 0; m < 2; ++m)
        #pragma unroll
        for (int k4 = 0; k4 < 4; ++k4) {
            const int row = m * 16 + l15;
            const int kc = k4 * 32 + l4 * 8;
            ahs[m][k4] = *(const bf16x8*)&HB[row * 256 + (kc ^ ((row & 7) << 3))];
            aht[m][k4] = *(const bf16x8*)&HB[row * 256 + ((128 + kc) ^ ((row & 7) << 3))];
        }
    __syncthreads();   // HB/HA overlap W2 tile — all reads done before staging

    // wave w stages exactly the rows it reads: S-rows [16w,16w+16), T-rows [64+16w,..)
    auto stageW2 = [&](int c2) {
        #pragma unroll
        for (int jj = 0; jj < 8; ++jj) {
            const int net  = jj >> 2;
            const int rloc = wave * 16 + (jj & 3) * 4 + (lane >> 4);
            const int pr   = c2 * 64 + rloc;
            const char* g = wsb + (size_t)(net ? OFF_TW2T : OFF_SW2T) * 2
                            + (size_t)pr * 256 + (lane & 15) * 16;
            void* l = LDSbuf + (net * 64 + wave * 16 + (jj & 3) * 4) * 256;
            __builtin_amdgcn_global_load_lds(
                (const __attribute__((address_space(1))) unsigned int*)g,
                (__attribute__((address_space(3))) unsigned int*)l, 16, 0, 0);
        }
    };

    float dsum[2][4] = {};
    fx2 zvA[2][4], zvB[2][4];
    float sbA, tbA, sbB, tbB;
    auto ldzEp = [&](fx2 (&zv)[2][4], float& sb, float& tb, int c2) {
        const int j = c2 * 64 + wave * 16 + l15;
        sb = s_b2[j];
        tb = t_b2[j];
        #pragma unroll
        for (int m = 0; m < 2; ++m)
            #pragma unroll
            for (int r = 0; r < 4; ++r)
                zv[m][r] = __builtin_nontemporal_load(
                    &zf2[(size_t)(brow + m * 16 + l4 * 4 + r) * 2048 + j]);
    };

    // iter c2: drain own stage(c2) (vmcnt leaves z(c2)+stores(c2-1)); ds_read own
    // rows -> regs; lgkm(0); stage(c2+1) over own rows; issue z(c2+1); MFMA+epilogue.
    auto l2iter = [&](fx2 (&zvCur)[2][4], float sbC, float tbC,
                      fx2 (&zvNxt)[2][4], float& sbN, float& tbN, int c2) {
        if (c2 == 0)
            asm volatile("s_waitcnt vmcnt(10)" ::: "memory");
        else
            asm volatile("s_waitcnt vmcnt(18)" ::: "memory");
        bf16x8 wfs[4], wft[4];
        #pragma unroll
        for (int k4 = 0; k4 < 4; ++k4) {
            const int rs = wave * 16 + l15;
            const int rt = 64 + wave * 16 + l15;
            const int kc = k4 * 64 + l4 * 16;
            wfs[k4] = *(const bf16x8*)(LDSbuf + rs * 256 + (kc ^ ((rs & 7) << 4)));
            wft[k4] = *(const bf16x8*)(LDSbuf + rt * 256 + (kc ^ ((rt & 7) << 4)));
        }
        asm volatile("s_waitcnt lgkmcnt(0)" ::: "memory");   // own tile reads done
        if (c2 + 1 < 32) {
            stageW2(c2 + 1);
            ldzEp(zvNxt, sbN, tbN, c2 + 1);
        }
        f32x4 acc2[2][2] = {};   // [net][m]
        #pragma unroll
        for (int k4 = 0; k4 < 4; ++k4)
            #pragma unroll
            for (int m = 0; m < 2; ++m) {
                acc2[0][m] = __builtin_amdgcn_mfma_f32_16x16x32_bf16(
                    ahs[m][k4], wfs[k4], acc2[0][m], 0, 0, 0);
                acc2[1][m] = __builtin_amdgcn_mfma_f32_16x16x32_bf16(
                    aht[m][k4], wft[k4], acc2[1][m], 0, 0, 0);
            }
        const int j = c2 * 64 + wave * 16 + l15;
        #pragma unroll
        for (int m = 0; m < 2; ++m)
            #pragma unroll
            for (int r = 0; r < 4; ++r) {
                const float sv = acc2[0][m][r] + sbC;
                const float tv = acc2[1][m][r] + tbC;
                const fx2 zp = zvCur[m][r];
                const float za = par ? zp.y : zp.x;
                const float zb = par ? zp.x : zp.y;
                const float fb = (zb - tv) * __expf(-sv);
                fx2 fv;
                if (par) { fv.x = fb; fv.y = za; }
                else     { fv.x = za; fv.y = fb; }
                __builtin_nontemporal_store(fv,
                    &ff2[(size_t)(brow + m * 16 + l4 * 4 + r) * 2048 + j]);
                dsum[m][r] += sv;
            }
    };

    // prologue: issue own W2(0) + z(0); no barrier needed (self-consumed)
    stageW2(0);
    ldzEp(zvA, sbA, tbA, 0);

    #pragma unroll 1
    for (int it = 0; it < 16; ++it) {
        l2iter(zvA, sbA, tbA, zvB, sbB, tbB, 2 * it);
        l2iter(zvB, sbB, tbB, zvA, sbA, tbA, 2 * it + 1);
    }

    // ---------------- d reduction ----------------
    __syncthreads();
    #pragma unroll
    for (int m = 0; m < 2; ++m)
        #pragma unroll
        for (int r = 0; r < 4; ++r) {
            float v = dsum[m][r];
            v += __shfl_xor(v, 1);
            v += __shfl_xor(v, 2);
            v += __shfl_xor(v, 4);
            v += __shfl_xor(v, 8);
            if (l15 == 0) Dred[wave * 32 + m * 16 + l4 * 4 + r] = v;
        }
    __syncthreads();
    if (tid < BM)
        d_vec[brow + tid] = Dred[tid] + Dred[32 + tid] + Dred[64 + tid] + Dred[96 + tid];
}

extern "C" void kernel_launch(void* const* d_in, const int* in_sizes, int n_in,
                              void* d_out, int out_size, void* d_ws, size_t ws_size,
                              hipStream_t stream) {
    const float* z   = (const float*)d_in[0];
    const float* sW0 = (const float*)d_in[1];
    const float* sW1 = (const float*)d_in[2];
    const float* sW2 = (const float*)d_in[3];
    const float* sb2 = (const float*)d_in[4];
    const float* tW0 = (const float*)d_in[5];
    const float* tW1 = (const float*)d_in[6];
    const float* tW2 = (const float*)d_in[7];
    const float* tb2 = (const float*)d_in[8];

    float* fout = (float*)d_out;
    float* dvec = fout + (size_t)BATCH * 4096;
    unsigned short* ws = (unsigned short*)d_ws;

    hipLaunchKernelGGL(conv_w, dim3(512), dim3(256), 0, stream,
                       sW0, sW1, sW2, tW0, tW1, tW2, ws);
    hipLaunchKernelGGL(coupling_main, dim3(BATCH / BM), dim3(256), 0, stream,
                       z, sb2, tb2, ws, fout, dvec);
}

// Round 19
// 189.730 us; speedup vs baseline: 3.3120x; 3.3120x over previous
//
#include <hip/hip_runtime.h>
#include <hip/hip_bf16.h>

#define BATCH  16384
#define SLOPE  0.2f
#define BM     32

typedef __attribute__((ext_vector_type(8))) short bf16x8;
typedef __attribute__((ext_vector_type(4))) float f32x4;
typedef __attribute__((ext_vector_type(4))) float fx4;
typedef __attribute__((ext_vector_type(2))) float fx2;

// ws layout (bf16 element offsets), weights TRANSPOSED as [N][K]; s/t contiguous.
// W0T and W2T rows are PRE-SWIZZLED in 16B units: unit u of row n at u ^ (n&7)
// (within each 128B chunk for W0T; within the 256B row for W2T).
#define OFF_SW0T 0         // [128][2048]
#define OFF_TW0T 262144
#define OFF_SW1T 524288    // [128][128] (unswizzled)
#define OFF_TW1T 540672
#define OFF_SW2T 557056    // [2048][128]
#define OFF_TW2T 819200

__device__ __forceinline__ unsigned short f2bf(float f) {
    unsigned int u = __float_as_uint(f);
    u += 0x7FFFu + ((u >> 16) & 1u);   // round-to-nearest-even
    return (unsigned short)(u >> 16);
}

// LDS-tiled transpose+convert: W0/W2 via 32x32 tiles (coalesced loads, swizzled
// bf16 writes within 128B windows); W1 scalar (tiny).
__global__ void conv_w(const float* __restrict__ sW0, const float* __restrict__ sW1,
                       const float* __restrict__ sW2, const float* __restrict__ tW0,
                       const float* __restrict__ tW1, const float* __restrict__ tW2,
                       unsigned short* __restrict__ ws) {
    __shared__ float T[32][33];
    const int b   = blockIdx.x;
    const int tid = threadIdx.x;
    const int r = tid >> 5, c = tid & 31;

    if (b < 512) {                       // W0 [2048k][128n] -> [128][2048], swz
        const int st   = b >> 8;         // 0=s, 1=t
        const int tile = b & 255;
        const int kt = tile & 63, nt = tile >> 6;
        const float* src = st ? tW0 : sW0;
        const int OFF = st ? OFF_TW0T : OFF_SW0T;
        #pragma unroll
        for (int i = 0; i < 4; ++i) {
            const int kk = kt * 32 + i * 8 + r;
            T[i * 8 + r][c] = src[kk * 128 + nt * 32 + c];
        }
        __syncthreads();
        #pragma unroll
        for (int i = 0; i < 4; ++i) {
            const int n = nt * 32 + i * 8 + r;
            const int k = kt * 32 + c;
            const int ks = (k & ~63) | ((((k >> 3) & 7) ^ (n & 7)) << 3) | (k & 7);
            ws[OFF + n * 2048 + ks] = f2bf(T[c][i * 8 + r]);
        }
    } else if (b < 1024) {               // W2 [128k][2048n] -> [2048][128], swz
        const int st   = (b - 512) >> 8;
        const int tile = (b - 512) & 255;
        const int kt = tile & 3, nt = tile >> 2;
        const float* src = st ? tW2 : sW2;
        const int OFF = st ? OFF_TW2T : OFF_SW2T;
        #pragma unroll
        for (int i = 0; i < 4; ++i) {
            const int kk = kt * 32 + i * 8 + r;
            T[i * 8 + r][c] = src[kk * 2048 + nt * 32 + c];
        }
        __syncthreads();
        #pragma unroll
        for (int i = 0; i < 4; ++i) {
            const int n = nt * 32 + i * 8 + r;
            const int k = kt * 32 + c;
            const int ks = ((((k >> 3) & 15) ^ (n & 7)) << 3) | (k & 7);
            ws[OFF + n * 128 + ks] = f2bf(T[c][i * 8 + r]);
        }
    } else {                             // W1 [128][128] -> transpose (no swz)
        const int j  = (b - 1024) * 256 + tid;   // 0..32767
        const int st = j >> 14;
        const int e  = j & 16383;
        const int k = e >> 7, n = e & 127;
        const float v = st ? tW1[e] : sW1[e];
        ws[(st ? OFF_TW1T : OFF_SW1T) + n * 128 + k] = f2bf(v);
    }
}

__global__ __launch_bounds__(256, 2) void coupling_main(
    const float* __restrict__ z,
    const float* __restrict__ s_b2,
    const float* __restrict__ t_b2,
    const unsigned short* __restrict__ ws,
    float* __restrict__ f_out,
    float* __restrict__ d_vec) {

    // LDS map:
    //   L0: Az dbuf [0,8K) (2x4K) | W0 dbuf [8K,72K) (2x32K)
    //   L1: HA [8K,24K) | HB [24K,40K)      (L0 regions dead)
    //   L2: W2 dbuf [0,64K) | Dred [64K,64K+512)
    __shared__ __align__(16) unsigned char LDSbuf[73728];
    unsigned short* HA = (unsigned short*)(LDSbuf + 8192);
    unsigned short* HB = (unsigned short*)(LDSbuf + 24576);
    float* Dred = (float*)(LDSbuf + 65536);

    const int tid  = threadIdx.x;
    const int wave = tid >> 6;
    const int lane = tid & 63;
    const int l15  = lane & 15;
    const int l4   = lane >> 4;
    const int brow = blockIdx.x * BM;

    const char* wsb = (const char*)ws;
    const fx4* __restrict__ zf4 = (const fx4*)z;
    const fx2* __restrict__ zf2 = (const fx2*)z;
    fx2* __restrict__ ff2 = (fx2*)f_out;

    // ---- L0 staging helpers ----
    auto ldzTo = [&](fx4 (&zr)[4], int c) {
        #pragma unroll
        for (int q = 0; q < 4; ++q) {
            const int f = tid + 256 * q;
            const int row = f >> 5, col16 = f & 31;
            zr[q] = __builtin_nontemporal_load(
                zf4 + (size_t)(brow + row) * 1024 + c * 32 + col16);
        }
    };
    auto wrzFrom = [&](fx4 (&zr)[4], int b) {
        #pragma unroll
        for (int q = 0; q < 4; ++q) {
            const int f = tid + 256 * q;
            const int row = f >> 5, col16 = f & 31;
            const int par = (col16 >> 4) & 1;
            const float a0 = par ? zr[q].y : zr[q].x;
            const float a1 = par ? zr[q].w : zr[q].z;
            const unsigned int pk = (unsigned int)f2bf(a0) | ((unsigned int)f2bf(a1) << 16);
            *(unsigned int*)(LDSbuf + b * 4096 + row * 128 +
                             (((col16 >> 2) ^ (row & 7)) << 4) + (col16 & 3) * 4) = pk;
        }
    };
    auto stageW0 = [&](int b, int c) {   // 256 g-rows x 128B (K-chunk c), pre-swz src
        #pragma unroll
        for (int jj = 0; jj < 8; ++jj) {
            const char* g = wsb + (size_t)(wave * 64 + jj * 8 + (lane >> 3)) * 4096
                            + c * 128 + (lane & 7) * 16;
            void* l = LDSbuf + 8192 + b * 32768 + (wave * 64 + jj * 8) * 128;
            __builtin_amdgcn_global_load_lds(
                (const __attribute__((address_space(1))) unsigned int*)g,
                (__attribute__((address_space(3))) unsigned int*)l, 16, 0, 0);
        }
    };

    f32x4 acc0[2][4] = {};   // [m][n2]
    auto cmp0 = [&](int cb) {
        const char* Az = (const char*)(LDSbuf + cb * 4096);
        const char* Wt = (const char*)(LDSbuf + 8192 + cb * 32768);
        bf16x8 af[2][2], wf[4][2];
        #pragma unroll
        for (int m = 0; m < 2; ++m)
            #pragma unroll
            for (int k2 = 0; k2 < 2; ++k2) {
                const int row = m * 16 + l15;
                af[m][k2] = *(const bf16x8*)(Az + row * 128 +
                              ((k2 * 64 + l4 * 16) ^ ((row & 7) << 4)));
            }
        #pragma unroll
        for (int n2 = 0; n2 < 4; ++n2)
            #pragma unroll
            for (int k2 = 0; k2 < 2; ++k2) {
                const int g = wave * 64 + n2 * 16 + l15;
                wf[n2][k2] = *(const bf16x8*)(Wt + g * 128 +
                               ((k2 * 64 + l4 * 16) ^ ((g & 7) << 4)));
            }
        #pragma unroll
        for (int n2 = 0; n2 < 4; ++n2)
            #pragma unroll
            for (int k2 = 0; k2 < 2; ++k2)
                #pragma unroll
                for (int m = 0; m < 2; ++m)
                    acc0[m][n2] = __builtin_amdgcn_mfma_f32_16x16x32_bf16(
                        af[m][k2], wf[n2][k2], acc0[m][n2], 0, 0, 0);
    };

    fx4 zA[4], zB[4];
    auto phase = [&](int p, int cb, fx4 (&zLd)[4], fx4 (&zWr)[4]) {
        if (p + 1 < 32) stageW0(cb ^ 1, p + 1);
        if (p + 2 < 32) ldzTo(zLd, p + 2);
        cmp0(cb);
        if (p + 1 < 32) wrzFrom(zWr, cb ^ 1);
        if (p + 2 < 32)
            asm volatile("s_waitcnt lgkmcnt(0) vmcnt(4)" ::: "memory");
        else
            asm volatile("s_waitcnt lgkmcnt(0) vmcnt(0)" ::: "memory");
        __builtin_amdgcn_s_barrier();
        __builtin_amdgcn_sched_barrier(0);
    };

    // ---------------- layer 0: h0 = leaky(z_a @ W0), unified g in [0,256) ----------------
    ldzTo(zB, 0);
    stageW0(0, 0);
    wrzFrom(zB, 0);          // Az0 <- tile 0
    ldzTo(zB, 1);            // zB <- tile 1
    asm volatile("s_waitcnt lgkmcnt(0) vmcnt(4)" ::: "memory");
    __builtin_amdgcn_s_barrier();
    __builtin_amdgcn_sched_barrier(0);

    #pragma unroll 1
    for (int gIt = 0; gIt < 16; ++gIt) {
        phase(2 * gIt,     0, zA, zB);
        phase(2 * gIt + 1, 1, zB, zA);
    }

    // leaky, h0 -> HA (swizzled [32][256])
    #pragma unroll
    for (int m = 0; m < 2; ++m)
        #pragma unroll
        for (int n2 = 0; n2 < 4; ++n2)
            #pragma unroll
            for (int r = 0; r < 4; ++r) {
                float v = acc0[m][n2][r];
                v = v > 0.0f ? v : SLOPE * v;
                const int row = m * 16 + l4 * 4 + r;
                const int col = wave * 64 + n2 * 16 + l15;
                HA[row * 256 + (col ^ ((row & 7) << 3))] = f2bf(v);
            }
    __syncthreads();

    // ---------------- layer 1: h1 = leaky(h0 @ W1) (direct global W1T) ----------------
    f32x4 acc1[2][4] = {};
    const int net1 = wave >> 1;
    #pragma unroll
    for (int k4 = 0; k4 < 4; ++k4) {
        bf16x8 ahv[2];
        #pragma unroll
        for (int m = 0; m < 2; ++m) {
            const int row = m * 16 + l15;
            ahv[m] = *(const bf16x8*)&HA[row * 256 +
                       ((net1 * 128 + k4 * 32 + l4 * 8) ^ ((row & 7) << 3))];
        }
        #pragma unroll
        for (int n2 = 0; n2 < 4; ++n2) {
            const bf16x8 w = *(const bf16x8*)&ws[OFF_SW1T +
                (size_t)(wave * 64 + n2 * 16 + l15) * 128 + k4 * 32 + l4 * 8];
            #pragma unroll
            for (int m = 0; m < 2; ++m)
                acc1[m][n2] = __builtin_amdgcn_mfma_f32_16x16x32_bf16(
                    ahv[m], w, acc1[m][n2], 0, 0, 0);
        }
    }
    __syncthreads();   // HA reads done
    #pragma unroll
    for (int m = 0; m < 2; ++m)
        #pragma unroll
        for (int n2 = 0; n2 < 4; ++n2)
            #pragma unroll
            for (int r = 0; r < 4; ++r) {
                float v = acc1[m][n2][r];
                v = v > 0.0f ? v : SLOPE * v;
                const int row = m * 16 + l4 * 4 + r;
                const int col = wave * 64 + n2 * 16 + l15;
                HB[row * 256 + (col ^ ((row & 7) << 3))] = f2bf(v);
            }
    __syncthreads();

    // ---------------- layer 2 + epilogue: W2 dbuf (R13 structure) ----------------
    const int par = wave >> 1;   // lattice-row parity of this wave's pairs

    // hoist A-fragments once (both nets)
    bf16x8 ahs[2][4], aht[2][4];   // [m][k4]
    #pragma unroll
    for (int m = 0; m < 2; ++m)
        #pragma unroll
        for (int k4 = 0; k4 < 4; ++k4) {
            const int row = m * 16 + l15;
            const int kc = k4 * 32 + l4 * 8;
            ahs[m][k4] = *(const bf16x8*)&HB[row * 256 + (kc ^ ((row & 7) << 3))];
            aht[m][k4] = *(const bf16x8*)&HB[row * 256 + ((128 + kc) ^ ((row & 7) << 3))];
        }
    __syncthreads();   // HB region overlaps W2 bufs — all reads done first

    auto stageW2 = [&](int b, int c2) {  // 128 rows (net*64+pair) x 256B, pre-swz src
        #pragma unroll
        for (int jj = 0; jj < 8; ++jj) {
            const int r  = wave * 32 + jj * 4 + (lane >> 4);
            const int pr = c2 * 64 + (r & 63);
            const char* g = wsb + (size_t)((r >> 6) ? OFF_TW2T : OFF_SW2T) * 2
                            + (size_t)pr * 256 + (lane & 15) * 16;
            void* l = LDSbuf + b * 32768 + (wave * 32 + jj * 4) * 256;
            __builtin_amdgcn_global_load_lds(
                (const __attribute__((address_space(1))) unsigned int*)g,
                (__attribute__((address_space(3))) unsigned int*)l, 16, 0, 0);
        }
    };

    float dsum[2][4] = {};

    auto l2body = [&](int c2, int cb) {
        const int j = c2 * 64 + wave * 16 + l15;      // global pair index
        const float sb = s_b2[j];
        const float tb = t_b2[j];
        fx2 zv[2][4];
        #pragma unroll
        for (int m = 0; m < 2; ++m)
            #pragma unroll
            for (int r = 0; r < 4; ++r)
                zv[m][r] = __builtin_nontemporal_load(
                    &zf2[(size_t)(brow + m * 16 + l4 * 4 + r) * 2048 + j]);

        bf16x8 wfs[4], wft[4];
        #pragma unroll
        for (int k4 = 0; k4 < 4; ++k4) {
            const int rs = wave * 16 + l15;
            const int rt = 64 + wave * 16 + l15;
            const int kc = k4 * 64 + l4 * 16;
            wfs[k4] = *(const bf16x8*)(LDSbuf + cb * 32768 + rs * 256 + (kc ^ ((rs & 7) << 4)));
            wft[k4] = *(const bf16x8*)(LDSbuf + cb * 32768 + rt * 256 + (kc ^ ((rt & 7) << 4)));
        }

        f32x4 acc2[2][2] = {};   // [net][m]
        #pragma unroll
        for (int k4 = 0; k4 < 4; ++k4)
            #pragma unroll
            for (int m = 0; m < 2; ++m) {
                acc2[0][m] = __builtin_amdgcn_mfma_f32_16x16x32_bf16(
                    ahs[m][k4], wfs[k4], acc2[0][m], 0, 0, 0);
                acc2[1][m] = __builtin_amdgcn_mfma_f32_16x16x32_bf16(
                    aht[m][k4], wft[k4], acc2[1][m], 0, 0, 0);
            }

        #pragma unroll
        for (int m = 0; m < 2; ++m)
            #pragma unroll
            for (int r = 0; r < 4; ++r) {
                const float sv = acc2[0][m][r] + sb;
                const float tv = acc2[1][m][r] + tb;
                const fx2 zp = zv[m][r];
                const float za = par ? zp.y : zp.x;
                const float zb = par ? zp.x : zp.y;
                const float fb = (zb - tv) * __expf(-sv);
                fx2 fv;
                if (par) { fv.x = fb; fv.y = za; }
                else     { fv.x = za; fv.y = fb; }
                __builtin_nontemporal_store(fv,
                    &ff2[(size_t)(brow + m * 16 + l4 * 4 + r) * 2048 + j]);
                dsum[m][r] += sv;
            }
    };

    stageW2(0, 0);
    __syncthreads();   // drain

    #pragma unroll 1
    for (int c2 = 0; c2 < 32; ++c2) {
        const int cb = c2 & 1;
        if (c2 < 31) stageW2(cb ^ 1, c2 + 1);
        l2body(c2, cb);
        __syncthreads();   // next tile staged & visible
    }

    // ---------------- d reduction ----------------
    #pragma unroll
    for (int m = 0; m < 2; ++m)
        #pragma unroll
        for (int r = 0; r < 4; ++r) {
            float v = dsum[m][r];
            v += __shfl_xor(v, 1);
            v += __shfl_xor(v, 2);
            v += __shfl_xor(v, 4);
            v += __shfl_xor(v, 8);
            if (l15 == 0) Dred[wave * 32 + m * 16 + l4 * 4 + r] = v;
        }
    __syncthreads();
    if (tid < BM)
        d_vec[brow + tid] = Dred[tid] + Dred[32 + tid] + Dred[64 + tid] + Dred[96 + tid];
}

extern "C" void kernel_launch(void* const* d_in, const int* in_sizes, int n_in,
                              void* d_out, int out_size, void* d_ws, size_t ws_size,
                              hipStream_t stream) {
    const float* z   = (const float*)d_in[0];
    const float* sW0 = (const float*)d_in[1];
    const float* sW1 = (const float*)d_in[2];
    const float* sW2 = (const float*)d_in[3];
    const float* sb2 = (const float*)d_in[4];
    const float* tW0 = (const float*)d_in[5];
    const float* tW1 = (const float*)d_in[6];
    const float* tW2 = (const float*)d_in[7];
    const float* tb2 = (const float*)d_in[8];

    float* fout = (float*)d_out;
    float* dvec = fout + (size_t)BATCH * 4096;
    unsigned short* ws = (unsigned short*)d_ws;

    hipLaunchKernelGGL(conv_w, dim3(1152), dim3(256), 0, stream,
                       sW0, sW1, sW2, tW0, tW1, tW2, ws);
    hipLaunchKernelGGL(coupling_main, dim3(BATCH / BM), dim3(256), 0, stream,
                       z, sb2, tb2, ws, fout, dvec);
}